// Round 1
// baseline (3197.267 us; speedup 1.0000x reference)
//
#include <hip/hip_runtime.h>

// Asterisk block: 4 branches of 5-tap dilated convs (dilation 2, K=5, PAD=4)
// over x[B=8,C=256,H=128,W=128] fp32 -> out[B,4*64,H,W] fp32.
// Closed-form tap offsets per branch g, tap k (d = 2k-4):
//   g=0: (0,  d)   g=1: (d, 0)   g=2: (d, -d)   g=3: (-d, d)
// Staged x rows i+{-4,-2,0,2,4} (index r: offset 2r-4), so:
//   g=0: r=2, dj=2k-4 | g=1: r=k, dj=0 | g=2: r=k, dj=4-2k | g=3: r=4-k, dj=2k-4

#define HH 128
#define WW 128
#define CIN 256
#define OUTC 64
#define KC 8                 // channels per LDS chunk
#define XS_ROW 136           // 128 + 2*4 halo
#define XS_ELEMS (KC*5*XS_ROW)
#define WS_ELEMS (5*KC*64)

template<int G>
__global__ void asterisk_conv(const float* __restrict__ x,
                              const float* __restrict__ w,
                              const float* __restrict__ bias,
                              float* __restrict__ out) {
    __shared__ float xs[XS_ELEMS];   // [cl*5 + r][136]
    __shared__ float ws[WS_ELEMS];   // [(k*KC + cl)*64 + oc]

    const int t   = threadIdx.x;     // 128 threads
    const int i   = blockIdx.x;      // output row
    const int b   = blockIdx.y;      // batch
    const int ocg = t >> 4;          // 0..7  -> oc = ocg*8 + u
    const int jg  = t & 15;          // 0..15 -> j  = jg + 16*v

    float acc[8][8];
#pragma unroll
    for (int u = 0; u < 8; ++u) {
        float bv = bias[ocg*8 + u];
#pragma unroll
        for (int v = 0; v < 8; ++v) acc[u][v] = bv;
    }

    const float* xb = x + (size_t)b * CIN * (HH*WW);

    for (int c0 = 0; c0 < CIN; c0 += KC) {
        __syncthreads();   // protect LDS from previous iteration's readers
        // ---- stage x halo tile: KC channels x 5 rows x 136 cols ----
        for (int e = t; e < XS_ELEMS; e += 128) {
            int rr  = e / XS_ROW;        // 0..39 = cl*5 + r
            int col = e - rr * XS_ROW;   // 0..135
            int cl  = rr / 5;
            int r   = rr - cl * 5;
            int row = i + 2*r - 4;
            int cx  = col - 4;
            float v = 0.f;
            if ((unsigned)row < HH && (unsigned)cx < WW)
                v = xb[((size_t)(c0 + cl))*(HH*WW) + row*WW + cx];
            xs[e] = v;
        }
        // ---- stage weights: ws[(k*KC+cl)*64+oc] = w[(oc*CIN + c0+cl)*5 + k] ----
        for (int e = t; e < WS_ELEMS; e += 128) {
            int oc = e & 63;
            int cc = e >> 6;             // k*KC + cl
            int k  = cc >> 3;
            int cl = cc & 7;
            ws[e] = w[((size_t)oc*CIN + (c0 + cl))*5 + k];
        }
        __syncthreads();

#pragma unroll
        for (int cl = 0; cl < KC; ++cl) {
#pragma unroll
            for (int k = 0; k < 5; ++k) {
                int r, dj;
                if (G == 0)      { r = 2;     dj = 2*k - 4; }
                else if (G == 1) { r = k;     dj = 0;       }
                else if (G == 2) { r = k;     dj = 4 - 2*k; }
                else             { r = 4 - k; dj = 2*k - 4; }
                const float* xrow = &xs[(cl*5 + r)*XS_ROW + 4 + dj + jg];
                float xv[8];
#pragma unroll
                for (int v = 0; v < 8; ++v) xv[v] = xrow[16*v];  // stride-16: bank-conflict-free
                const float* wp = &ws[(k*KC + cl)*64 + ocg*8];
                float4 wa = *(const float4*)wp;
                float4 wb = *(const float4*)(wp + 4);
                float wr[8] = {wa.x, wa.y, wa.z, wa.w, wb.x, wb.y, wb.z, wb.w};
#pragma unroll
                for (int u = 0; u < 8; ++u)
#pragma unroll
                    for (int v = 0; v < 8; ++v)
                        acc[u][v] = fmaf(wr[u], xv[v], acc[u][v]);
            }
        }
    }

    // ---- write out: out[b, G*64+oc, i, j] ----
#pragma unroll
    for (int u = 0; u < 8; ++u) {
        int oc = ocg*8 + u;
        float* op = out + ((((size_t)b*(4*OUTC)) + G*OUTC + oc)*HH + i)*WW;
#pragma unroll
        for (int v = 0; v < 8; ++v)
            op[jg + 16*v] = acc[u][v];
    }
}

extern "C" void kernel_launch(void* const* d_in, const int* in_sizes, int n_in,
                              void* d_out, int out_size, void* d_ws, size_t ws_size,
                              hipStream_t stream) {
    const float* x    = (const float*)d_in[0];
    const float* w_h  = (const float*)d_in[1];
    const float* b_h  = (const float*)d_in[2];
    const float* w_v  = (const float*)d_in[3];
    const float* b_v  = (const float*)d_in[4];
    const float* w_d1 = (const float*)d_in[5];
    const float* b_d1 = (const float*)d_in[6];
    const float* w_d2 = (const float*)d_in[7];
    const float* b_d2 = (const float*)d_in[8];
    float* out = (float*)d_out;

    dim3 grid(HH, 8);   // (row, batch); 1024 blocks per branch
    dim3 blk(128);
    asterisk_conv<0><<<grid, blk, 0, stream>>>(x, w_h,  b_h,  out);
    asterisk_conv<1><<<grid, blk, 0, stream>>>(x, w_v,  b_v,  out);
    asterisk_conv<2><<<grid, blk, 0, stream>>>(x, w_d1, b_d1, out);
    asterisk_conv<3><<<grid, blk, 0, stream>>>(x, w_d2, b_d2, out);
}

// Round 2
// 120.686 us; speedup vs baseline: 26.4925x; 26.4925x over previous
//
#include <hip/hip_runtime.h>
#include <hip/hip_bf16.h>

// Fused Asterisk block as implicit GEMM on MFMA.
// Branch/tap geometry (verified in round 0), tap k, d=2k-4, staged row r: off 2r-4:
//   g=0: r=2,   dj=2k-4 | g=1: r=k, dj=0 | g=2: r=k, dj=4-2k | g=3: r=4-k, dj=2k-4
// Per block (b,i): LDS tile xs[r=5][col=136][c=32] bf16 (slot-swizzled), 4 waves = 4
// branches, each an M=64 x N=128 GEMM over K=1280 via mfma_f32_16x16x32_bf16.
// Weights pre-repacked (bf16, A-fragment order) into d_ws: needs 655,360 B.

typedef __attribute__((ext_vector_type(8))) __bf16 bf16x8;
typedef __attribute__((ext_vector_type(4))) float f32x4;

#define HH 128
#define WW 128
#define CIN 256
#define NCHUNK 8
#define CHUNK 32
#define COLS 136
#define XS_ELEMS (5*COLS*CHUNK)   // 21760 bf16 = 43520 B
#define WPG (40*64*32)            // 81920 bf16 per branch

__device__ __forceinline__ ushort f2bf(float f) {
    union { float f; unsigned u; } v; v.f = f;
    unsigned r = v.u + 0x7FFF + ((v.u >> 16) & 1);   // RNE
    return (ushort)(r >> 16);
}

// wp[((g*40 + s)*64 + m)*32 + kk] = bf16( w_g[(m*256 + (s/5)*32 + kk)*5 + (s%5)] )
__global__ void repack_w(const float* __restrict__ w0, const float* __restrict__ w1,
                         const float* __restrict__ w2, const float* __restrict__ w3,
                         ushort* __restrict__ wp) {
    int idx = blockIdx.x * 256 + threadIdx.x;   // 0..327679
    int g   = idx / WPG;
    int rem = idx - g * WPG;
    int s   = rem >> 11;
    int r2  = rem & 2047;
    int m   = r2 >> 5;
    int kk  = r2 & 31;
    int k   = s % 5;
    int cc  = s / 5;
    const float* w = (g == 0) ? w0 : (g == 1) ? w1 : (g == 2) ? w2 : w3;
    wp[idx] = f2bf(w[(m * CIN + cc * 32 + kk) * 5 + k]);
}

__global__ __launch_bounds__(256, 2)
void asterisk_mfma(const float* __restrict__ x,
                   const ushort* __restrict__ wp,
                   const float* __restrict__ b0, const float* __restrict__ b1,
                   const float* __restrict__ b2, const float* __restrict__ b3,
                   float* __restrict__ out) {
    __shared__ __align__(16) short xs[XS_ELEMS];  // [r][col][slot-swizzled c]

    const int t    = threadIdx.x;
    const int lane = t & 63;
    const int wid  = t >> 6;        // branch g
    const int m16  = lane & 15;
    const int h    = lane >> 4;

    // XCD-bijective swizzle: one batch per XCD (1024 blocks, 1024%8==0)
    int id = blockIdx.x;
    int sw = (id & 7) * 128 + (id >> 3);
    const int b = sw >> 7;
    const int i = sw & 127;

    // ---- zero LDS pad columns (cols 0..3, 132..135) for all r, c ----
    for (int e = t; e < 5 * 8 * CHUNK; e += 256) {
        int r  = e >> 8;
        int pc = (e >> 5) & 7;
        int c  = e & 31;
        int col = (pc < 4) ? pc : 128 + pc;
        xs[(r * COLS + col) * CHUNK + c] = 0;
    }
    // ---- zero out-of-bounds row planes (rows i+2r-4 outside [0,128)) ----
    for (int r = 0; r < 5; ++r) {
        int row = i + 2 * r - 4;
        if ((unsigned)row >= HH) {
            for (int e = t; e < COLS * CHUNK; e += 256)
                xs[r * COLS * CHUNK + e] = 0;
        }
    }

    // ---- accumulators init = bias ----
    const float* bias = (wid == 0) ? b0 : (wid == 1) ? b1 : (wid == 2) ? b2 : b3;
    f32x4 acc[4][8];
#pragma unroll
    for (int mb = 0; mb < 4; ++mb) {
        f32x4 bv;
#pragma unroll
        for (int rr = 0; rr < 4; ++rr) bv[rr] = bias[mb * 16 + h * 4 + rr];
#pragma unroll
        for (int nb = 0; nb < 8; ++nb) acc[mb][nb] = bv;
    }

    const int cg = t >> 5;          // channel group (4 ch) 0..7
    const int q  = t & 31;          // col quad: real cols 4q..4q+3
    const float* xb = x + (size_t)b * CIN * HH * WW;
    const ushort* wg = wp + (size_t)wid * WPG;

    for (int cc = 0; cc < NCHUNK; ++cc) {
        __syncthreads();            // previous chunk's readers done
        // ---- stage: 32 channels x 5 rows x 128 cols, fp32 -> bf16, transposed ----
        {
            int c0 = cc * CHUNK + cg * 4;
            int slot = cg >> 1;
            int sub  = (cg & 1) * 4;
            const float* srcc = xb + (size_t)c0 * HH * WW + q * 4;
#pragma unroll
            for (int r = 0; r < 5; ++r) {
                int row = i + 2 * r - 4;
                if ((unsigned)row < HH) {
                    const float* src = srcc + (size_t)row * WW;
                    float4 v0 = *(const float4*)(src);
                    float4 v1 = *(const float4*)(src + HH * WW);
                    float4 v2 = *(const float4*)(src + 2 * HH * WW);
                    float4 v3 = *(const float4*)(src + 3 * HH * WW);
#pragma unroll
                    for (int jj = 0; jj < 4; ++jj) {
                        int col = q * 4 + 4 + jj;                 // padded col
                        int sl  = slot ^ ((col >> 2) & 3);        // XOR swizzle
                        float f0 = ((const float*)&v0)[jj];
                        float f1 = ((const float*)&v1)[jj];
                        float f2 = ((const float*)&v2)[jj];
                        float f3 = ((const float*)&v3)[jj];
                        __hip_bfloat162 lo = __float22bfloat162_rn(make_float2(f0, f1));
                        __hip_bfloat162 hi = __float22bfloat162_rn(make_float2(f2, f3));
                        uint2 pk;
                        pk.x = *(unsigned*)&lo;   // c0+0 low, c0+1 high
                        pk.y = *(unsigned*)&hi;
                        *(uint2*)&xs[(r * COLS + col) * CHUNK + sl * 8 + sub] = pk;
                    }
                }
            }
        }
        __syncthreads();
        // ---- compute: 5 taps over this 32-channel chunk ----
#pragma unroll
        for (int k = 0; k < 5; ++k) {
            int r  = (wid == 0) ? 2 : (wid == 3 ? 4 - k : k);
            int dj = (wid == 1) ? 0 : (wid == 2 ? 4 - 2 * k : 2 * k - 4);
            // A fragments: lane holds W[m16+16mb][kk = 8h..8h+7], contiguous bf16
            const ushort* wk = wg + (size_t)((cc * 5 + k) * 64 + m16) * 32 + h * 8;
            bf16x8 a[4];
#pragma unroll
            for (int mb = 0; mb < 4; ++mb)
                a[mb] = *(const bf16x8*)(wk + mb * 16 * 32);
            int col0 = m16 + dj + 4;                     // padded col, nb adds 16
            int sl   = h ^ ((col0 >> 2) & 3);            // invariant in nb (16>>2==4)
            const short* xr = &xs[(r * COLS + col0) * CHUNK + sl * 8];
#pragma unroll
            for (int nb = 0; nb < 8; ++nb) {
                bf16x8 bf = *(const bf16x8*)(xr + nb * 16 * CHUNK);
#pragma unroll
                for (int mb = 0; mb < 4; ++mb)
                    acc[mb][nb] = __builtin_amdgcn_mfma_f32_16x16x32_bf16(
                        a[mb], bf, acc[mb][nb], 0, 0, 0);
            }
        }
    }

    // ---- epilogue: D[m][n], m = mb*16 + h*4 + rr (oc), n = nb*16 + m16 (col) ----
    size_t obase = (((size_t)b * 256 + wid * 64) * HH + i) * WW;
#pragma unroll
    for (int mb = 0; mb < 4; ++mb)
#pragma unroll
        for (int rr = 0; rr < 4; ++rr) {
            float* op = out + obase + (size_t)(mb * 16 + h * 4 + rr) * HH * WW + m16;
#pragma unroll
            for (int nb = 0; nb < 8; ++nb)
                op[nb * 16] = acc[mb][nb][rr];
        }
}

extern "C" void kernel_launch(void* const* d_in, const int* in_sizes, int n_in,
                              void* d_out, int out_size, void* d_ws, size_t ws_size,
                              hipStream_t stream) {
    const float* x    = (const float*)d_in[0];
    const float* w_h  = (const float*)d_in[1];
    const float* b_h  = (const float*)d_in[2];
    const float* w_v  = (const float*)d_in[3];
    const float* b_v  = (const float*)d_in[4];
    const float* w_d1 = (const float*)d_in[5];
    const float* b_d1 = (const float*)d_in[6];
    const float* w_d2 = (const float*)d_in[7];
    const float* b_d2 = (const float*)d_in[8];
    float* out = (float*)d_out;
    ushort* wpack = (ushort*)d_ws;   // needs 655,360 B

    repack_w<<<1280, 256, 0, stream>>>(w_h, w_v, w_d1, w_d2, wpack);
    asterisk_mfma<<<1024, 256, 0, stream>>>(x, wpack, b_h, b_v, b_d1, b_d2, out);
}

// Round 3
// 120.369 us; speedup vs baseline: 26.5622x; 1.0026x over previous
//
#include <hip/hip_runtime.h>
#include <hip/hip_bf16.h>

// Fused Asterisk block as implicit GEMM on MFMA.
// Branch/tap geometry (verified round 0), tap k, d=2k-4, staged row r: off 2r-4:
//   g=0: r=2, dj=2k-4 | g=1: r=k, dj=0 | g=2: r=k, dj=4-2k | g=3: r=4-k, dj=2k-4
// Per block (b,i): LDS tile xs[r=5][col=136][c=32] bf16, 4 waves = 4 branches,
// each an M=64 x N=128 GEMM over K=1280 via mfma_f32_16x16x32_bf16.
// LDS swizzle (BOTH write and read sides):
//   octet slot = owner ^ ((col>>2)&3)        -> spreads ds_read_b128 (2-way, free)
//   short-index bit5 ^= (col>>4)&1           -> spreads ds_write_b64 to 4-way floor
// Weights pre-repacked (bf16, A-fragment order) into d_ws: 655,360 B.

typedef __attribute__((ext_vector_type(8))) __bf16 bf16x8;
typedef __attribute__((ext_vector_type(4))) float f32x4;

#define HH 128
#define WW 128
#define CIN 256
#define NCHUNK 8
#define CHUNK 32
#define COLS 136
#define XS_ELEMS (5*COLS*CHUNK)   // 21760 bf16 = 43520 B
#define WPG (40*64*32)            // 81920 bf16 per branch

__device__ __forceinline__ ushort f2bf(float f) {
    union { float f; unsigned u; } v; v.f = f;
    unsigned r = v.u + 0x7FFF + ((v.u >> 16) & 1);   // RNE
    return (ushort)(r >> 16);
}

// wp[((g*40 + s)*64 + m)*32 + kk] = bf16( w_g[(m*256 + (s/5)*32 + kk)*5 + (s%5)] )
__global__ void repack_w(const float* __restrict__ w0, const float* __restrict__ w1,
                         const float* __restrict__ w2, const float* __restrict__ w3,
                         ushort* __restrict__ wp) {
    int idx = blockIdx.x * 256 + threadIdx.x;   // 0..327679
    int g   = idx / WPG;
    int rem = idx - g * WPG;
    int s   = rem >> 11;
    int r2  = rem & 2047;
    int m   = r2 >> 5;
    int kk  = r2 & 31;
    int k   = s % 5;
    int cc  = s / 5;
    const float* w = (g == 0) ? w0 : (g == 1) ? w1 : (g == 2) ? w2 : w3;
    wp[idx] = f2bf(w[(m * CIN + cc * 32 + kk) * 5 + k]);
}

__global__ __launch_bounds__(256, 4)
void asterisk_mfma(const float* __restrict__ x,
                   const ushort* __restrict__ wp,
                   const float* __restrict__ b0, const float* __restrict__ b1,
                   const float* __restrict__ b2, const float* __restrict__ b3,
                   float* __restrict__ out) {
    __shared__ __align__(16) short xs[XS_ELEMS];

    const int t    = threadIdx.x;
    const int lane = t & 63;
    const int wid  = t >> 6;        // branch g
    const int m16  = lane & 15;
    const int h    = lane >> 4;

    // XCD-bijective swizzle: one batch per XCD (1024 blocks, 1024%8==0)
    int id = blockIdx.x;
    int sw = (id & 7) * 128 + (id >> 3);
    const int b = sw >> 7;
    const int i = sw & 127;

    // ---- zero LDS pad columns (cols 0..3, 132..135; pair-aligned regions) ----
    for (int e = t; e < 5 * 8 * CHUNK; e += 256) {
        int r  = e >> 8;
        int pc = (e >> 5) & 7;
        int c  = e & 31;
        int col = (pc < 4) ? pc : 128 + pc;
        xs[(r * COLS + col) * CHUNK + c] = 0;
    }
    // ---- zero out-of-bounds row planes ----
    for (int r = 0; r < 5; ++r) {
        int row = i + 2 * r - 4;
        if ((unsigned)row >= HH) {
            for (int e = t; e < COLS * CHUNK; e += 256)
                xs[r * COLS * CHUNK + e] = 0;
        }
    }

    // ---- accumulators init = bias ----
    const float* bias = (wid == 0) ? b0 : (wid == 1) ? b1 : (wid == 2) ? b2 : b3;
    f32x4 acc[4][8];
#pragma unroll
    for (int mb = 0; mb < 4; ++mb) {
        f32x4 bv;
#pragma unroll
        for (int rr = 0; rr < 4; ++rr) bv[rr] = bias[mb * 16 + h * 4 + rr];
#pragma unroll
        for (int nb = 0; nb < 8; ++nb) acc[mb][nb] = bv;
    }

    const int cg = t >> 5;          // channel nibble group (4 ch) 0..7
    const int q  = t & 31;          // col quad: real cols 4q..4q+3
    const float* xb = x + (size_t)b * CIN * HH * WW;
    const ushort* wg = wp + (size_t)wid * WPG;

    for (int cc = 0; cc < NCHUNK; ++cc) {
        __syncthreads();            // previous chunk's readers done
        // ---- stage: 32 channels x 5 rows x 128 cols, fp32 -> bf16, transposed ----
        {
            int c0 = cc * CHUNK + cg * 4;
            int slot = cg >> 1;              // owning octet
            int sub  = (cg & 1) * 4;         // 4-short half of octet
            const float* srcc = xb + (size_t)c0 * HH * WW + q * 4;
#pragma unroll
            for (int r = 0; r < 5; ++r) {
                int row = i + 2 * r - 4;
                if ((unsigned)row < HH) {
                    const float* src = srcc + (size_t)row * WW;
                    float4 v0 = *(const float4*)(src);
                    float4 v1 = *(const float4*)(src + HH * WW);
                    float4 v2 = *(const float4*)(src + 2 * HH * WW);
                    float4 v3 = *(const float4*)(src + 3 * HH * WW);
#pragma unroll
                    for (int jj = 0; jj < 4; ++jj) {
                        int col = q * 4 + 4 + jj;                 // padded col
                        int sl  = slot ^ ((col >> 2) & 3);        // octet swizzle
                        float f0 = ((const float*)&v0)[jj];
                        float f1 = ((const float*)&v1)[jj];
                        float f2 = ((const float*)&v2)[jj];
                        float f3 = ((const float*)&v3)[jj];
                        __hip_bfloat162 lo = __float22bfloat162_rn(make_float2(f0, f1));
                        __hip_bfloat162 hi = __float22bfloat162_rn(make_float2(f2, f3));
                        uint2 pk;
                        pk.x = *(unsigned*)&lo;
                        pk.y = *(unsigned*)&hi;
                        int wi = (r * COLS + col) * CHUNK + sl * 8 + sub;
                        wi ^= ((col >> 4) & 1) << 5;              // bit5 spread
                        *(uint2*)&xs[wi] = pk;
                    }
                }
            }
        }
        __syncthreads();
        // ---- compute: 5 taps over this 32-channel chunk, tap-pipelined A ----
        const ushort* wc = wg + (size_t)(cc * 5 * 64 * 32) + m16 * 32 + h * 8;
        bf16x8 a_cur[4], a_nxt[4];
#pragma unroll
        for (int mb = 0; mb < 4; ++mb)
            a_cur[mb] = *(const bf16x8*)(wc + mb * 16 * 32);
#pragma unroll
        for (int k = 0; k < 5; ++k) {
            if (k < 4) {
                const ushort* wk1 = wc + (size_t)(k + 1) * 64 * 32;
#pragma unroll
                for (int mb = 0; mb < 4; ++mb)
                    a_nxt[mb] = *(const bf16x8*)(wk1 + mb * 16 * 32);
            }
            int r  = (wid == 0) ? 2 : (wid == 3 ? 4 - k : k);
            int dj = (wid == 1) ? 0 : (wid == 2 ? 4 - 2 * k : 2 * k - 4);
            int col0 = m16 + dj + 4;                     // padded col, nb adds 16
            int sl   = h ^ ((col0 >> 2) & 3);
            int base = (r * COLS + col0) * CHUNK + sl * 8;
            base ^= ((col0 >> 4) & 1) << 5;              // bit5 spread (read side)
#pragma unroll
            for (int nb = 0; nb < 8; ++nb) {
                int idx = (base + nb * 16 * CHUNK) ^ ((nb & 1) << 5);
                bf16x8 bf = *(const bf16x8*)(&xs[idx]);
#pragma unroll
                for (int mb = 0; mb < 4; ++mb)
                    acc[mb][nb] = __builtin_amdgcn_mfma_f32_16x16x32_bf16(
                        a_cur[mb], bf, acc[mb][nb], 0, 0, 0);
            }
            if (k < 4) {
#pragma unroll
                for (int mb = 0; mb < 4; ++mb) a_cur[mb] = a_nxt[mb];
            }
        }
    }

    // ---- epilogue: D[m][n], m = mb*16 + h*4 + rr (oc), n = nb*16 + m16 (col) ----
    size_t obase = (((size_t)b * 256 + wid * 64) * HH + i) * WW;
#pragma unroll
    for (int mb = 0; mb < 4; ++mb)
#pragma unroll
        for (int rr = 0; rr < 4; ++rr) {
            float* op = out + obase + (size_t)(mb * 16 + h * 4 + rr) * HH * WW + m16;
#pragma unroll
            for (int nb = 0; nb < 8; ++nb)
                op[nb * 16] = acc[mb][nb][rr];
        }
}

extern "C" void kernel_launch(void* const* d_in, const int* in_sizes, int n_in,
                              void* d_out, int out_size, void* d_ws, size_t ws_size,
                              hipStream_t stream) {
    const float* x    = (const float*)d_in[0];
    const float* w_h  = (const float*)d_in[1];
    const float* b_h  = (const float*)d_in[2];
    const float* w_v  = (const float*)d_in[3];
    const float* b_v  = (const float*)d_in[4];
    const float* w_d1 = (const float*)d_in[5];
    const float* b_d1 = (const float*)d_in[6];
    const float* w_d2 = (const float*)d_in[7];
    const float* b_d2 = (const float*)d_in[8];
    float* out = (float*)d_out;
    ushort* wpack = (ushort*)d_ws;   // needs 655,360 B

    repack_w<<<1280, 256, 0, stream>>>(w_h, w_v, w_d1, w_d2, wpack);
    asterisk_mfma<<<1024, 256, 0, stream>>>(x, wpack, b_h, b_v, b_d1, b_d2, out);
}